// Round 1
// baseline (108.282 us; speedup 1.0000x reference)
//
#include <hip/hip_runtime.h>
#include <cstdint>

#ifndef __has_builtin
#define __has_builtin(x) 0
#endif

// Extract bit `off` of x and sign-extend: returns 0 or -1 (all-ones mask).
__device__ __forceinline__ int sbfe1(unsigned x, int off) {
#if __has_builtin(__builtin_amdgcn_sbfe)
    return __builtin_amdgcn_sbfe((int)x, off, 1);
#else
    return ((int)(x << (31 - off))) >> 31;
#endif
}

// Build the packed mask word for (t, g): 16 pairs (r,q), bit layout:
//   bit pi      : sign of gp term   (1 = negative)
//   bit 16+pi   : wedge condition   (m subset of i)
//   bit 32+pi   : inner condition   (m&i==0  or  i subset of m)
// where i = 4t+r, m = 4g+q, j = m^i, pi = r*4+q.
__device__ __forceinline__ unsigned long long make_mask_word(
        const float* __restrict__ gp_signs, int t, int g) {
    unsigned long long word = 0ull;
#pragma unroll
    for (int r = 0; r < 4; ++r) {
#pragma unroll
        for (int q = 0; q < 4; ++q) {
            const int i = 4 * t + r;
            const int m = 4 * g + q;
            const int j = m ^ i;
            const int pi = r * 4 + q;
            const float s = gp_signs[j * 256 + m];
            if (s < 0.0f)                          word |= (1ull << pi);
            if ((m & ~i) == 0)                     word |= (1ull << (16 + pi));
            if (((m & i) == 0) || ((i & ~m) == 0)) word |= (1ull << (32 + pi));
        }
    }
    return word;
}

__global__ void clifford_prep_kernel(const float* __restrict__ gp_signs,
                                     unsigned long long* __restrict__ tbl) {
    const int tid = blockIdx.x * blockDim.x + threadIdx.x;  // [0, 4096)
    const int t = tid & 63;
    const int g = tid >> 6;
    tbl[tid] = make_mask_word(gp_signs, t, g);  // tbl index == g*64 + t
}

__global__ __launch_bounds__(256) void clifford_main_kernel(
        const float* __restrict__ A, const float* __restrict__ B,
        const unsigned long long* __restrict__ tbl,
        const float* __restrict__ gp_signs,
        float* __restrict__ out) {
    __shared__ float As[256];
    __shared__ float Bs[256];
    __shared__ unsigned long long masks[4096];  // 32 KB; reused as reduction space

    const int tid = threadIdx.x;
    const int row = blockIdx.x;  // [0, 1024)

    As[tid] = A[row * 256 + tid];
    Bs[tid] = B[row * 256 + tid];

    if (tbl) {
#pragma unroll
        for (int k2 = 0; k2 < 16; ++k2)
            masks[k2 * 256 + tid] = tbl[k2 * 256 + tid];
    } else {
        // Fallback if workspace too small: compute masks locally.
        for (int k2 = 0; k2 < 16; ++k2) {
            const int idx = k2 * 256 + tid;
            masks[idx] = make_mask_word(gp_signs, idx & 63, idx >> 6);
        }
    }
    __syncthreads();

    const int w = tid >> 6;  // wave id: m-range split
    const int t = tid & 63;  // thread owns outputs i = 4t + r

    float gp[4] = {0.f, 0.f, 0.f, 0.f};
    float we[4] = {0.f, 0.f, 0.f, 0.f};
    float in_[4] = {0.f, 0.f, 0.f, 0.f};

    const float4* As4 = (const float4*)As;
    const float4* Bs4 = (const float4*)Bs;

    for (int gg = 0; gg < 16; ++gg) {
        const int g = (w << 4) | gg;          // this wave's m-group
        const float4 b4 = Bs4[g];             // broadcast (uniform address)
        const float4 a4 = As4[g ^ t];         // XOR-permuted: conflict-free
        const unsigned long long mw = masks[(g << 6) | t];
        const unsigned lo = (unsigned)mw;
        const unsigned hi = (unsigned)(mw >> 32);
        const float av[4] = {a4.x, a4.y, a4.z, a4.w};
        const float bv[4] = {b4.x, b4.y, b4.z, b4.w};
#pragma unroll
        for (int r = 0; r < 4; ++r) {
#pragma unroll
            for (int u = 0; u < 4; ++u) {
                const int q = u ^ r;          // m = 4g + q pairs with a-elem u
                const int pi = (r << 2) | q;  // static bit position
                const float p = av[u] * bv[q];
                unsigned pu = __float_as_uint(p);
                pu ^= ((unsigned)sbfe1(lo, pi) & 0x80000000u);  // apply sign
                const float sp = __uint_as_float(pu);
                gp[r] += sp;
                we[r] += __uint_as_float(pu & (unsigned)sbfe1(lo, 16 + pi));
                in_[r] += __uint_as_float(pu & (unsigned)sbfe1(hi, pi));
            }
        }
    }

    __syncthreads();
    // Reuse mask LDS as reduction space: red[w][prod][i], 4*3*256 floats = 12 KB
    float* red = (float*)masks;
#pragma unroll
    for (int r = 0; r < 4; ++r) {
        red[w * 768 + 0   + 4 * t + r] = gp[r];
        red[w * 768 + 256 + 4 * t + r] = we[r];
        red[w * 768 + 512 + 4 * t + r] = in_[r];
    }
    __syncthreads();

#pragma unroll
    for (int prod = 0; prod < 3; ++prod) {
        const int o = prod * 256 + tid;
        const float s = red[0 * 768 + o] + red[1 * 768 + o] +
                        red[2 * 768 + o] + red[3 * 768 + o];
        out[prod * 262144 + row * 256 + tid] = s;  // [3][1024][256]
    }
}

extern "C" void kernel_launch(void* const* d_in, const int* in_sizes, int n_in,
                              void* d_out, int out_size, void* d_ws, size_t ws_size,
                              hipStream_t stream) {
    const float* A = (const float*)d_in[0];
    const float* B = (const float*)d_in[1];
    const float* gp_signs = (const float*)d_in[5];
    float* out = (float*)d_out;

    unsigned long long* tbl = nullptr;
    if (ws_size >= 4096 * sizeof(unsigned long long)) {
        tbl = (unsigned long long*)d_ws;
        clifford_prep_kernel<<<16, 256, 0, stream>>>(gp_signs, tbl);
    }
    clifford_main_kernel<<<1024, 256, 0, stream>>>(A, B, tbl, gp_signs, out);
}

// Round 2
// 103.527 us; speedup vs baseline: 1.0459x; 1.0459x over previous
//
#include <hip/hip_runtime.h>
#include <cstdint>

#ifndef __has_builtin
#define __has_builtin(x) 0
#endif

// Extract bit `off` of x and sign-extend: returns 0 or -1 (all-ones mask).
__device__ __forceinline__ int sbfe1(unsigned x, int off) {
#if __has_builtin(__builtin_amdgcn_sbfe)
    return __builtin_amdgcn_sbfe((int)x, off, 1);
#else
    return ((int)(x << (31 - off))) >> 31;
#endif
}

// Packed mask word for (t, g): 16 pairs (r,q), bit layout:
//   bit pi    : sign of gp term (1 = negative)
//   bit 16+pi : wedge condition (m subset of i)
//   bit 32+pi : inner condition (m&i==0 or i subset of m)
// where i = 4t+r, m = 4g+q, j = m^i, pi = r*4+q.
__device__ __forceinline__ unsigned long long make_mask_word(
        const float* __restrict__ gp_signs, int t, int g) {
    unsigned long long word = 0ull;
#pragma unroll
    for (int r = 0; r < 4; ++r) {
#pragma unroll
        for (int q = 0; q < 4; ++q) {
            const int i = 4 * t + r;
            const int m = 4 * g + q;
            const int j = m ^ i;
            const int pi = r * 4 + q;
            const float s = gp_signs[j * 256 + m];
            if (s < 0.0f)                          word |= (1ull << pi);
            if ((m & ~i) == 0)                     word |= (1ull << (16 + pi));
            if (((m & i) == 0) || ((i & ~m) == 0)) word |= (1ull << (32 + pi));
        }
    }
    return word;
}

__global__ void clifford_prep_kernel(const float* __restrict__ gp_signs,
                                     unsigned long long* __restrict__ tbl) {
    const int tid = blockIdx.x * blockDim.x + threadIdx.x;  // [0, 4096)
    tbl[tid] = make_mask_word(gp_signs, tid & 63, tid >> 6);  // idx = g*64 + t
}

// 2 rows per block; 4 waves split the m-range (16 groups each); each thread
// owns outputs i = 4t+r for BOTH rows -> mask extraction amortized 2x.
__global__ __launch_bounds__(256) void clifford_main_kernel(
        const float* __restrict__ A, const float* __restrict__ B,
        const unsigned long long* __restrict__ tbl,
        const float* __restrict__ gp_signs,
        float* __restrict__ out) {
    __shared__ float As[2][256];
    __shared__ float Bs[2][256];
    __shared__ unsigned long long masks[4096];  // 32 KB; reused for reduction

    const int tid = threadIdx.x;
    const int r0 = blockIdx.x * 2;  // rows r0, r0+1

    As[0][tid] = A[r0 * 256 + tid];
    As[1][tid] = A[r0 * 256 + 256 + tid];
    Bs[0][tid] = B[r0 * 256 + tid];
    Bs[1][tid] = B[r0 * 256 + 256 + tid];

    if (tbl) {
#pragma unroll
        for (int k2 = 0; k2 < 16; ++k2)
            masks[k2 * 256 + tid] = tbl[k2 * 256 + tid];
    } else {
        for (int k2 = 0; k2 < 16; ++k2) {
            const int idx = k2 * 256 + tid;
            masks[idx] = make_mask_word(gp_signs, idx & 63, idx >> 6);
        }
    }
    __syncthreads();

    const int w = tid >> 6;  // wave id: m-range split
    const int t = tid & 63;  // thread owns outputs i = 4t+r

    float acc[2][3][4];
#pragma unroll
    for (int row = 0; row < 2; ++row)
#pragma unroll
        for (int p = 0; p < 3; ++p)
#pragma unroll
            for (int r = 0; r < 4; ++r) acc[row][p][r] = 0.f;

    const float4* As40 = (const float4*)As[0];
    const float4* As41 = (const float4*)As[1];
    const float4* Bs40 = (const float4*)Bs[0];
    const float4* Bs41 = (const float4*)Bs[1];

#pragma unroll 4
    for (int gg = 0; gg < 16; ++gg) {
        const int g = (w << 4) | gg;                 // this wave's m-group
        const unsigned long long mw = masks[(g << 6) | t];
        const float4 a40 = As40[g ^ t];              // XOR-permuted float4
        const float4 a41 = As41[g ^ t];
        const float4 b40 = Bs40[g];                  // broadcast
        const float4 b41 = Bs41[g];
        const unsigned lo = (unsigned)mw;
        const unsigned hi = (unsigned)(mw >> 32);
        const float av0[4] = {a40.x, a40.y, a40.z, a40.w};
        const float av1[4] = {a41.x, a41.y, a41.z, a41.w};
        const float bv0[4] = {b40.x, b40.y, b40.z, b40.w};
        const float bv1[4] = {b41.x, b41.y, b41.z, b41.w};
#pragma unroll
        for (int r = 0; r < 4; ++r) {
#pragma unroll
            for (int u = 0; u < 4; ++u) {
                const int q = u ^ r;                 // m = 4g+q pairs with a-elem u
                const int pi = (r << 2) | q;         // static bit position
                const unsigned smask = ((unsigned)sbfe1(lo, pi)) & 0x80000000u;
                const unsigned wm = (unsigned)sbfe1(lo, 16 + pi);
                const unsigned im = (unsigned)sbfe1(hi, pi);
                {
                    const float p = av0[u] * bv0[q];
                    const unsigned pu = __float_as_uint(p) ^ smask;
                    acc[0][0][r] += __uint_as_float(pu);
                    acc[0][1][r] += __uint_as_float(pu & wm);
                    acc[0][2][r] += __uint_as_float(pu & im);
                }
                {
                    const float p = av1[u] * bv1[q];
                    const unsigned pu = __float_as_uint(p) ^ smask;
                    acc[1][0][r] += __uint_as_float(pu);
                    acc[1][1][r] += __uint_as_float(pu & wm);
                    acc[1][2][r] += __uint_as_float(pu & im);
                }
            }
        }
    }

    __syncthreads();
    // Reuse mask LDS: red[(w*2+row)*3+prod][256], 24 floats/thread = 24 KB
    float* red = (float*)masks;
#pragma unroll
    for (int row = 0; row < 2; ++row)
#pragma unroll
        for (int prod = 0; prod < 3; ++prod)
#pragma unroll
            for (int r = 0; r < 4; ++r)
                red[(((w * 2 + row) * 3 + prod) << 8) + 4 * t + r] = acc[row][prod][r];
    __syncthreads();

#pragma unroll
    for (int row = 0; row < 2; ++row)
#pragma unroll
        for (int prod = 0; prod < 3; ++prod) {
            float s = 0.f;
#pragma unroll
            for (int ww = 0; ww < 4; ++ww)
                s += red[(((ww * 2 + row) * 3 + prod) << 8) + tid];
            out[prod * 262144 + (r0 + row) * 256 + tid] = s;  // [3][1024][256]
        }
}

extern "C" void kernel_launch(void* const* d_in, const int* in_sizes, int n_in,
                              void* d_out, int out_size, void* d_ws, size_t ws_size,
                              hipStream_t stream) {
    const float* A = (const float*)d_in[0];
    const float* B = (const float*)d_in[1];
    const float* gp_signs = (const float*)d_in[5];
    float* out = (float*)d_out;

    unsigned long long* tbl = nullptr;
    if (ws_size >= 4096 * sizeof(unsigned long long)) {
        tbl = (unsigned long long*)d_ws;
        clifford_prep_kernel<<<16, 256, 0, stream>>>(gp_signs, tbl);
    }
    clifford_main_kernel<<<512, 256, 0, stream>>>(A, B, tbl, gp_signs, out);
}

// Round 3
// 94.962 us; speedup vs baseline: 1.1403x; 1.0902x over previous
//
#include <hip/hip_runtime.h>
#include <cstdint>

#ifndef __has_builtin
#define __has_builtin(x) 0
#endif

// Extract bit `off` of x and sign-extend: returns 0 or -1 (all-ones mask).
__device__ __forceinline__ int sbfe1(unsigned x, int off) {
#if __has_builtin(__builtin_amdgcn_sbfe)
    return __builtin_amdgcn_sbfe((int)x, off, 1);
#else
    return ((int)(x << (31 - off))) >> 31;
#endif
}

// Packed mask word for (t, g), computed from pure bit math (matches the
// reference's integer sign construction exactly). 16 pairs (r,q), layout:
//   bit pi    : sign of gp term (1 = negative)
//   bit 16+pi : wedge condition (m subset of i)
//   bit 32+pi : inner condition (m&i==0 or i subset of m)
// where i = 4t+r, m = 4g+q, j = m^i, pi = r*4+q.
__device__ __forceinline__ unsigned long long make_mask_word_bits(int t, int g) {
    unsigned long long word = 0ull;
#pragma unroll
    for (int r = 0; r < 4; ++r) {
#pragma unroll
        for (int q = 0; q < 4; ++q) {
            const int i = 4 * t + r;
            const int m = 4 * g + q;
            const int j = m ^ i;
            const int pi = r * 4 + q;
            int cnt = 0;
#pragma unroll
            for (int p = 0; p < 8; ++p)
                cnt += ((j >> p) & 1) ? __popc(m & ((1 << p) - 1)) : 0;
            if (cnt & 1)                           word |= (1ull << pi);
            if ((m & ~i) == 0)                     word |= (1ull << (16 + pi));
            if (((m & i) == 0) || ((i & ~m) == 0)) word |= (1ull << (32 + pi));
        }
    }
    return word;
}

__global__ void clifford_prep_kernel(unsigned long long* __restrict__ tbl) {
    const int tid = blockIdx.x * blockDim.x + threadIdx.x;  // [0, 4096)
    tbl[tid] = make_mask_word_bits(tid & 63, tid >> 6);     // idx = g*64 + t
}

// 4 rows per block, 512 threads; 8 waves split the m-range (8 groups each).
// Mask extraction amortized over 4 rows: 4 shared ops + 7 ops/row per term.
__global__ __launch_bounds__(512) void clifford_main_kernel(
        const float* __restrict__ A, const float* __restrict__ B,
        const unsigned long long* __restrict__ tbl,
        float* __restrict__ out) {
    __shared__ float As[4][256];
    __shared__ float Bs[4][256];
    __shared__ unsigned long long masks[4096];  // 32 KB; reused as red[8][4][256]

    const int tid = threadIdx.x;   // 0..511
    const int r0 = blockIdx.x * 4; // rows r0..r0+3

    {
        const int row = tid >> 8;  // 0..1
        const int c = tid & 255;
        As[row][c]     = A[(r0 + row) * 256 + c];
        As[row + 2][c] = A[(r0 + row + 2) * 256 + c];
        Bs[row][c]     = B[(r0 + row) * 256 + c];
        Bs[row + 2][c] = B[(r0 + row + 2) * 256 + c];
    }
    if (tbl) {
#pragma unroll
        for (int k2 = 0; k2 < 8; ++k2)
            masks[k2 * 512 + tid] = tbl[k2 * 512 + tid];
    } else {
        for (int k2 = 0; k2 < 8; ++k2) {
            const int idx = k2 * 512 + tid;
            masks[idx] = make_mask_word_bits(idx & 63, idx >> 6);
        }
    }
    __syncthreads();

    const int w = tid >> 6;  // wave id 0..7: m-range split
    const int t = tid & 63;  // thread owns outputs i = 4t+r

    float acc[4][3][4] = {};  // [row][prod][r]

#pragma unroll 2
    for (int gg = 0; gg < 8; ++gg) {
        const int g = (w << 3) | gg;  // this wave's m-group
        const unsigned long long mw = masks[(g << 6) | t];
        float av[4][4], bv[4][4];
#pragma unroll
        for (int row = 0; row < 4; ++row) {
            const float4 a4 = ((const float4*)As[row])[g ^ t];  // XOR-permuted
            const float4 b4 = ((const float4*)Bs[row])[g];      // broadcast
            av[row][0] = a4.x; av[row][1] = a4.y; av[row][2] = a4.z; av[row][3] = a4.w;
            bv[row][0] = b4.x; bv[row][1] = b4.y; bv[row][2] = b4.z; bv[row][3] = b4.w;
        }
        const unsigned lo = (unsigned)mw;
        const unsigned hi = (unsigned)(mw >> 32);
#pragma unroll
        for (int r = 0; r < 4; ++r) {
#pragma unroll
            for (int u = 0; u < 4; ++u) {
                const int q = u ^ r;          // m = 4g+q pairs with a-elem u
                const int pi = (r << 2) | q;  // static bit position
                const unsigned smask = ((unsigned)sbfe1(lo, pi)) & 0x80000000u;
                const unsigned wm = (unsigned)sbfe1(lo, 16 + pi);
                const unsigned im = (unsigned)sbfe1(hi, pi);
#pragma unroll
                for (int row = 0; row < 4; ++row) {
                    const float p = av[row][u] * bv[row][q];
                    const unsigned pu = __float_as_uint(p) ^ smask;
                    acc[row][0][r] += __uint_as_float(pu);
                    acc[row][1][r] += __uint_as_float(pu & wm);
                    acc[row][2][r] += __uint_as_float(pu & im);
                }
            }
        }
    }

    // Chunked cross-wave reduction reusing the mask LDS (32 KB per pass):
    // red[w][row][r*64 + t] holds acc for component comp = 4t+r.
    float* red = (float*)masks;
#pragma unroll
    for (int p = 0; p < 3; ++p) {
        __syncthreads();
#pragma unroll
        for (int row = 0; row < 4; ++row)
#pragma unroll
            for (int r = 0; r < 4; ++r)
                red[w * 1024 + row * 256 + (r << 6) + t] = acc[row][p][r];
        __syncthreads();
#pragma unroll
        for (int c = 0; c < 2; ++c) {
            const int idx = (c << 9) + tid;  // 0..1023
            const int row = idx >> 8;
            const int comp = idx & 255;
            const int swz = row * 256 + (comp >> 2) + ((comp & 3) << 6);
            float s = 0.f;
#pragma unroll
            for (int ww = 0; ww < 8; ++ww) s += red[ww * 1024 + swz];
            out[p * 262144 + (r0 + row) * 256 + comp] = s;  // [3][1024][256]
        }
    }
}

extern "C" void kernel_launch(void* const* d_in, const int* in_sizes, int n_in,
                              void* d_out, int out_size, void* d_ws, size_t ws_size,
                              hipStream_t stream) {
    const float* A = (const float*)d_in[0];
    const float* B = (const float*)d_in[1];
    float* out = (float*)d_out;

    unsigned long long* tbl = nullptr;
    if (ws_size >= 4096 * sizeof(unsigned long long)) {
        tbl = (unsigned long long*)d_ws;
        clifford_prep_kernel<<<64, 64, 0, stream>>>(tbl);
    }
    clifford_main_kernel<<<256, 512, 0, stream>>>(A, B, tbl, out);
}